// Round 11
// baseline (1675.095 us; speedup 1.0000x reference)
//
#include <hip/hip_runtime.h>
#include <hip/hip_bf16.h>
#include <stdint.h>
#include <stddef.h>

// DecoderStepLayer R10-M: MEASUREMENT ROUND #2 (epilogue + degeneracy break).
// Self-side reps: qp2 x30, attn x5, comb x60, vproj16 x60, skg_wo x30 -> all
// five land in rocprof top-5 above the 77us harness fills. Cross side and FFN
// run production (rep=1). Structural change banked: vproj un-k-split (grid 16,
// nc=32, double-buffered) writes ob directly; ovred + opart eliminated.

#define DEV __device__ __forceinline__

typedef __attribute__((ext_vector_type(8))) short bf16x8;
typedef __attribute__((ext_vector_type(4))) short bf16x4;
typedef __attribute__((ext_vector_type(4))) float f32x4;

DEV unsigned short f2b(float f){
  union { __hip_bfloat16 h; unsigned short u; } cv;
  cv.h = __float2bfloat16(f);
  return cv.u;
}
DEV float b2f(unsigned short u){
  union { unsigned int i; float f; } cv;
  cv.i = ((unsigned int)u) << 16;
  return cv.f;
}
DEV f32x4 mfma16(bf16x8 a, bf16x8 b, f32x4 c){
  return __builtin_amdgcn_mfma_f32_16x16x32_bf16(a, b, c, 0, 0, 0);
}

// ---------------------------------------------------------------------------
// qp2: qpb[b,h,d] = bf16( sum_k wk[h,d,k] * (0.125*sum_d' src[b,d']*wq[h,d',k]) )
__global__ __launch_bounds__(256) void g_qp2(const float* __restrict__ src,
    const float* __restrict__ wq, const float* __restrict__ wk,
    unsigned short* __restrict__ qpb, int rep){
  int u = blockIdx.x, b = u >> 4, h = u & 15;
  int t = threadIdx.x;
  __shared__ float red[256];
  __shared__ float Qs[64];
  #pragma unroll 1
  for(int rp=0; rp<rep; ++rp){
    __syncthreads();
    {
      int k = t & 63, q = t >> 6;
      const float* s = src + (size_t)b*1024 + q*256;
      const float* w = wq + (size_t)h*65536 + (size_t)(q*256)*64 + k;
      float a0=0.f,a1=0.f,a2=0.f,a3=0.f;
      for(int d=0; d<256; d+=4){
        a0 += s[d]   * w[(size_t)d*64];
        a1 += s[d+1] * w[(size_t)(d+1)*64];
        a2 += s[d+2] * w[(size_t)(d+2)*64];
        a3 += s[d+3] * w[(size_t)(d+3)*64];
      }
      red[t] = a0+a1+a2+a3;
      __syncthreads();
      if(t < 64) Qs[t] = (red[t]+red[t+64]+red[t+128]+red[t+192])*0.125f;
      __syncthreads();
    }
    for(int i=0;i<4;++i){
      int d = t + i*256;
      const float* w = wk + ((size_t)h*1024 + d)*64;
      float acc = 0.f;
      #pragma unroll
      for(int k4=0;k4<16;++k4){
        float4 wv4 = *(const float4*)(w + k4*4);
        acc += wv4.x*Qs[k4*4] + wv4.y*Qs[k4*4+1] + wv4.z*Qs[k4*4+2] + wv4.w*Qs[k4*4+3];
      }
      qpb[(size_t)u*1024 + d] = f2b(acc);
    }
  }
}

// ---------------------------------------------------------------------------
// attn: grid 1024 = (ns 64, b 16). Block = 32 rows, 2 chunks of 16.
__global__ __launch_bounds__(256) void g_attn(const float* __restrict__ kvsrc,
    const float* __restrict__ decrow, const unsigned short* __restrict__ qpb,
    float* __restrict__ scr, unsigned short* __restrict__ partb,
    float* __restrict__ msum, int lsrc, int rep){
  int u = blockIdx.x, ns = u & 63, b = u >> 6;
  int t = threadIdx.x, lane = t & 63, w = t >> 6;
  int r = lane & 15, hi = lane >> 4;
  int slice0 = ns*32;

  __shared__ unsigned short lt[1024*20];
  __shared__ float red[1024];
  __shared__ unsigned short p_lds[16*40];
  __shared__ float f_lds[16];

  #pragma unroll 1
  for(int rp=0; rp<rep; ++rp){
    __syncthreads();
    float4 ld[16];
    auto ISSUE = [&](int c){
      int row = slice0 + c*16 + r;
      const float* rpp = (row < lsrc) ? kvsrc + ((size_t)b*lsrc + row)*1024
                                      : decrow + (size_t)b*1024;
      rpp += w*256 + hi*8;
      #pragma unroll
      for(int kk=0; kk<8; ++kk){
        ld[kk*2+0] = *(const float4*)(rpp + kk*32);
        ld[kk*2+1] = *(const float4*)(rpp + kk*32 + 4);
      }
    };

    ISSUE(0);
    for(int i=t; i<16*40; i+=256) p_lds[i] = 0;

    bf16x8 qf[8];
    {
      const unsigned short* qp = qpb + ((size_t)b*16 + r)*1024 + w*256 + hi*8;
      #pragma unroll
      for(int kk=0;kk<8;++kk) qf[kk] = *(const bf16x8*)(qp + kk*32);
    }

    f32x4 acc[16];
    #pragma unroll
    for(int i=0;i<16;++i) acc[i] = (f32x4){0.f,0.f,0.f,0.f};
    float m_run = -1e30f, s_run = 0.f;

    __syncthreads();
    for(int c=0; c<2; ++c){
      f32x4 s_acc = {0.f,0.f,0.f,0.f};
      int colw = r ^ ((hi & 1) << 3);
      #pragma unroll
      for(int kk=0; kk<8; ++kk){
        float4 a0 = ld[kk*2], a1 = ld[kk*2+1];
        bf16x8 v;
        v[0]=(short)f2b(a0.x); v[1]=(short)f2b(a0.y);
        v[2]=(short)f2b(a0.z); v[3]=(short)f2b(a0.w);
        v[4]=(short)f2b(a1.x); v[5]=(short)f2b(a1.y);
        v[6]=(short)f2b(a1.z); v[7]=(short)f2b(a1.w);
        unsigned short* pt = &lt[(w*256 + hi*8 + kk*32)*20 + colw];
        #pragma unroll
        for(int j=0;j<8;++j) pt[j*20] = (unsigned short)v[j];
        s_acc = mfma16(v, qf[kk], s_acc);
      }
      if(c < 1) ISSUE(c+1);
      *(f32x4*)&red[t*4] = s_acc;
      __syncthreads();                     // (A)

      f32x4 ss = *(const f32x4*)&red[(0*64+lane)*4];
      ss += *(const f32x4*)&red[(1*64+lane)*4];
      ss += *(const f32x4*)&red[(2*64+lane)*4];
      ss += *(const f32x4*)&red[(3*64+lane)*4];
      float sf[4] = {ss[0], ss[1], ss[2], ss[3]};
      float mc = fmaxf(fmaxf(sf[0],sf[1]), fmaxf(sf[2],sf[3]));
      mc = fmaxf(mc, __shfl_xor(mc, 16));
      mc = fmaxf(mc, __shfl_xor(mc, 32));
      float nm = fmaxf(m_run, mc);
      float fch = __expf(m_run - nm);
      float pvv[4]; float ps = 0.f;
      #pragma unroll
      for(int i=0;i<4;++i){ pvv[i] = __expf(sf[i]-nm); ps += pvv[i]; }
      ps += __shfl_xor(ps, 16);
      ps += __shfl_xor(ps, 32);
      s_run = s_run*fch + ps;
      m_run = nm;
      if(w == 0){
        #pragma unroll
        for(int i=0;i<4;++i) p_lds[r*40 + hi*4 + i] = f2b(pvv[i]);
        if(hi == 0) f_lds[r] = fch;
        float* sp = scr + ((size_t)b*16 + r)*2048 + slice0 + c*16 + hi*4;
        *(float4*)sp = (float4){sf[0], sf[1], sf[2], sf[3]};
      }
      __syncthreads();                     // (B)

      f32x4 fv = *(const f32x4*)&f_lds[hi*4];
      bf16x8 pa = *(const bf16x8*)&p_lds[r*40 + hi*8];
      #pragma unroll
      for(int dc=0; dc<16; ++dc){
        acc[dc] *= fv;
        int d = w*256 + dc*16 + r;
        int col0 = (((hi & 1) ^ ((r >> 3) & 1)) << 3);
        bf16x4 blo = *(const bf16x4*)&lt[d*20 + col0];
        bf16x4 bhi = *(const bf16x4*)&lt[d*20 + col0 + 4];
        bf16x8 bv;
        bv[0]=blo[0]; bv[1]=blo[1]; bv[2]=blo[2]; bv[3]=blo[3];
        bv[4]=bhi[0]; bv[5]=bhi[1]; bv[6]=bhi[2]; bv[7]=bhi[3];
        acc[dc] = mfma16(pa, bv, acc[dc]);
      }
      __syncthreads();                     // (C)
    }
    unsigned short* pl = lt;               // reuse: [h 16][d 1024]
    #pragma unroll
    for(int dc=0; dc<16; ++dc)
      #pragma unroll
      for(int i=0;i<4;++i)
        pl[(hi*4+i)*1024 + w*256 + dc*16 + r] = f2b(acc[dc][i]);
    __syncthreads();
    {
      const uint4* s4 = (const uint4*)pl;
      uint4* d4 = (uint4*)(partb + (((size_t)b*64 + ns)*16)*1024);
      #pragma unroll
      for(int j=0;j<8;++j) d4[t + j*256] = s4[t + j*256];
    }
    if(w==0 && hi==0){
      msum[(((size_t)b*64 + ns)*16 + r)*2 + 0] = m_run;
      msum[(((size_t)b*64 + ns)*16 + r)*2 + 1] = s_run;
    }
  }
}

// ---------------------------------------------------------------------------
// comb: grid (dq 4, bh 256), blk 256. weights + probs + normalized bf16 ctx.
__global__ __launch_bounds__(256) void g_comb(const float* __restrict__ msum,
    const float* __restrict__ scr, const unsigned short* __restrict__ partb,
    float* __restrict__ attn_out, unsigned short* __restrict__ ctxb, int rep){
  int dq = blockIdx.x, bh = blockIdx.y, b = bh >> 4, h = bh & 15;
  int t = threadIdx.x;
  __shared__ float e_lds[64];
  __shared__ float Mi[2];
  #pragma unroll 1
  for(int rp=0; rp<rep; ++rp){
    __syncthreads();
    if(t < 64){
      float2 ms = *(const float2*)&msum[(((size_t)b*64 + t)*16 + h)*2];
      float M = ms.x;
      #pragma unroll
      for(int o=1; o<64; o<<=1) M = fmaxf(M, __shfl_xor(M, o));
      float e = __expf(ms.x - M)*ms.y;
      float S = e;
      #pragma unroll
      for(int o=1; o<64; o<<=1) S += __shfl_xor(S, o);
      e_lds[t] = __expf(ms.x - M)/S;
      if(t == 0){ Mi[0] = M; Mi[1] = 1.f/S; }
    }
    __syncthreads();
    float M = Mi[0], inv = Mi[1];
    const float* sp = scr + (size_t)bh*2048 + dq*512;
    float* po = attn_out + (size_t)bh*2048 + dq*512;
    po[t]     = __expf(sp[t]     - M)*inv;
    po[t+256] = __expf(sp[t+256] - M)*inv;
    int d = dq*256 + t;
    const unsigned short* pb0 = partb + ((size_t)b*64*16 + h)*1024 + d;
    float acc = 0.f;
    #pragma unroll 8
    for(int ns=0; ns<64; ++ns)
      acc += e_lds[ns]*b2f(pb0[(size_t)ns*16384]);
    ctxb[(size_t)bh*1024 + d] = f2b(acc);
  }
}

// ---------------------------------------------------------------------------
// vproj16: ob[b][h*64+v] = bf16( sum_d ctxb[b][h][d]*wv[h][d][v] )
// grid 16 (h), blk 256. MFMA, nc=32, double-buffered. No k-split, no ovred.
__global__ __launch_bounds__(256) void g_vproj16(const float* __restrict__ wv,
    const unsigned short* __restrict__ ctxb, unsigned short* __restrict__ ob,
    int rep){
  int h = blockIdx.x;
  __shared__ unsigned short lt[2][64*40];
  int t = threadIdx.x, lane = t & 63, w = t >> 6;
  int k_loc = t >> 3, n_off = (t & 7)*8;
  const unsigned short* apb = ctxb + (size_t)(lane & 15)*16384 + (size_t)h*1024
                              + (lane >> 4)*8;
  const float* Wb = wv + (size_t)h*65536;      // [1024 d][64 v]
  #pragma unroll 1
  for(int rp=0; rp<rep; ++rp){
    __syncthreads();
    f32x4 acc = {0.f,0.f,0.f,0.f};
    float4 x0, x1;
    auto LD = [&](int c){
      const float* wp = Wb + (size_t)(c*32 + k_loc)*64 + n_off;
      x0 = *(const float4*)wp;
      x1 = *(const float4*)(wp + 4);
    };
    auto ST = [&](int buf){
      unsigned short* p = &lt[buf][0];
      p[(n_off+0)*40 + k_loc] = f2b(x0.x);
      p[(n_off+1)*40 + k_loc] = f2b(x0.y);
      p[(n_off+2)*40 + k_loc] = f2b(x0.z);
      p[(n_off+3)*40 + k_loc] = f2b(x0.w);
      p[(n_off+4)*40 + k_loc] = f2b(x1.x);
      p[(n_off+5)*40 + k_loc] = f2b(x1.y);
      p[(n_off+6)*40 + k_loc] = f2b(x1.z);
      p[(n_off+7)*40 + k_loc] = f2b(x1.w);
    };
    LD(0); ST(0);
    for(int c=0; c<32; ++c){
      if(c+1 < 32) LD(c+1);
      __syncthreads();
      bf16x8 af = *(const bf16x8*)(apb + c*32);
      bf16x8 bv = *(const bf16x8*)&lt[c&1][(w*16 + (lane & 15))*40 + (lane >> 4)*8];
      acc = mfma16(af, bv, acc);
      if(c+1 < 32) ST((c+1)&1);
    }
    int col = w*16 + (lane & 15);
    int r0 = (lane >> 4)*4;
    #pragma unroll
    for(int i=0;i<4;++i)
      ob[(size_t)(r0+i)*1024 + h*64 + col] = f2b(acc[i]);
  }
}

// ---------------------------------------------------------------------------
// LN( sum_ks parts + bias + resid ) * g + bb -> xout [+ bf16]. grid 16.
__global__ __launch_bounds__(256) void g_ln(const float* __restrict__ parts, int KS,
    const float* __restrict__ bias, const float* __restrict__ resid,
    const float* __restrict__ g, const float* __restrict__ bb,
    float* __restrict__ xout, unsigned short* __restrict__ xb16){
  int b = blockIdx.x, t = threadIdx.x;
  __shared__ float red[256];
  const float4* bias4  = (const float4*)bias;
  const float4* resid4 = (const float4*)resid + (size_t)b*256;
  const float4* parts4 = (const float4*)parts;
  float4 s = bias4[t];
  { float4 rr = resid4[t]; s.x+=rr.x; s.y+=rr.y; s.z+=rr.z; s.w+=rr.w; }
  #pragma unroll 4
  for(int k=0;k<KS;++k){
    float4 pp = parts4[((size_t)k*16 + b)*256 + t];
    s.x+=pp.x; s.y+=pp.y; s.z+=pp.z; s.w+=pp.w;
  }
  red[t] = s.x+s.y+s.z+s.w; __syncthreads();
  for(int off=128; off>0; off>>=1){ if(t<off) red[t]+=red[t+off]; __syncthreads(); }
  float mean = red[0]*(1.f/1024.f); __syncthreads();
  float dx=s.x-mean, dy=s.y-mean, dz=s.z-mean, dw=s.w-mean;
  red[t] = dx*dx+dy*dy+dz*dz+dw*dw; __syncthreads();
  for(int off=128; off>0; off>>=1){ if(t<off) red[t]+=red[t+off]; __syncthreads(); }
  float rstd = rsqrtf(red[0]*(1.f/1024.f) + 1e-5f);
  float4 g4 = ((const float4*)g)[t], b4 = ((const float4*)bb)[t];
  float4 y;
  y.x = dx*rstd*g4.x + b4.x;
  y.y = dy*rstd*g4.y + b4.y;
  y.z = dz*rstd*g4.z + b4.z;
  y.w = dw*rstd*g4.w + b4.w;
  if(xout) ((float4*)xout)[(size_t)b*256 + t] = y;
  if(xb16){
    ushort4 uu;
    uu.x = f2b(y.x); uu.y = f2b(y.y); uu.z = f2b(y.z); uu.w = f2b(y.w);
    ((ushort4*)xb16)[(size_t)b*256 + t] = uu;
  }
}

// ---------------------------------------------------------------------------
// skinny GEMM: part[ks,b,n] = A[16,Kslice] @ W[Kslice,N]
__global__ __launch_bounds__(256) void g_skg(const float* __restrict__ W,
    const unsigned short* __restrict__ A, float* __restrict__ part,
    int N, int K, int KS, int rep){
  int nt = blockIdx.x, ks = blockIdx.y;
  int Ksl = K / KS, k0b = ks * Ksl, n0 = nt*64;
  int nc = Ksl >> 5;
  __shared__ unsigned short lt[2][64*40];
  int t = threadIdx.x, lane = t & 63, w = t >> 6;
  int k_loc = t >> 3, n_off = (t & 7)*8;
  const unsigned short* apb = A + (size_t)(lane & 15)*K + (lane >> 4)*8 + k0b;
  #pragma unroll 1
  for(int rp=0; rp<rep; ++rp){
    __syncthreads();
    f32x4 acc = {0.f,0.f,0.f,0.f};
    float4 x0, x1;
    auto LD = [&](int c){
      const float* wp = W + (size_t)(k0b + c*32 + k_loc)*N + n0 + n_off;
      x0 = *(const float4*)wp;
      x1 = *(const float4*)(wp + 4);
    };
    auto ST = [&](int buf){
      unsigned short* p = &lt[buf][0];
      p[(n_off+0)*40 + k_loc] = f2b(x0.x);
      p[(n_off+1)*40 + k_loc] = f2b(x0.y);
      p[(n_off+2)*40 + k_loc] = f2b(x0.z);
      p[(n_off+3)*40 + k_loc] = f2b(x0.w);
      p[(n_off+4)*40 + k_loc] = f2b(x1.x);
      p[(n_off+5)*40 + k_loc] = f2b(x1.y);
      p[(n_off+6)*40 + k_loc] = f2b(x1.z);
      p[(n_off+7)*40 + k_loc] = f2b(x1.w);
    };
    LD(0); ST(0);
    for(int c=0; c<nc; ++c){
      if(c+1 < nc) LD(c+1);
      __syncthreads();
      bf16x8 af = *(const bf16x8*)(apb + c*32);
      bf16x8 bv = *(const bf16x8*)&lt[c&1][(w*16 + (lane & 15))*40 + (lane >> 4)*8];
      acc = mfma16(af, bv, acc);
      if(c+1 < nc) ST((c+1)&1);
    }
    int col = n0 + w*16 + (lane & 15);
    int r0 = (lane >> 4)*4;
    #pragma unroll
    for(int i=0;i<4;++i)
      part[ ((size_t)ks*16 + r0 + i)*(size_t)N + col ] = acc[i];
  }
}

// relu( sum_ks fparts + b1 ) -> h1 bf16 [16][4096]. grid 64.
__global__ __launch_bounds__(256) void g_relu(const float* __restrict__ parts, int KS,
    const float* __restrict__ b1, unsigned short* __restrict__ h1){
  int i = blockIdx.x*256 + threadIdx.x;
  int b = i >> 10, f4 = i & 1023;
  float4 s = ((const float4*)b1)[f4];
  #pragma unroll 4
  for(int k=0;k<KS;++k){
    float4 pp = ((const float4*)parts)[((size_t)k*16 + b)*1024 + f4];
    s.x+=pp.x; s.y+=pp.y; s.z+=pp.z; s.w+=pp.w;
  }
  ushort4 uu;
  uu.x = f2b(fmaxf(s.x,0.f)); uu.y = f2b(fmaxf(s.y,0.f));
  uu.z = f2b(fmaxf(s.z,0.f)); uu.w = f2b(fmaxf(s.w,0.f));
  ((ushort4*)h1)[i] = uu;
}

// ---------------------------------------------------------------------------
extern "C" void kernel_launch(void* const* d_in, const int* in_sizes, int n_in,
                              void* d_out, int out_size, void* d_ws, size_t ws_size,
                              hipStream_t stream){
  const float* dec    = (const float*)d_in[0];
  const float* hist   = (const float*)d_in[1];
  const float* enc    = (const float*)d_in[2];
  const float* wq_s   = (const float*)d_in[3];
  const float* wk_s   = (const float*)d_in[4];
  const float* wv_s   = (const float*)d_in[5];
  const float* wo_s   = (const float*)d_in[6];
  const float* bo_s   = (const float*)d_in[7];
  const float* ln1_g  = (const float*)d_in[8];
  const float* ln1_b  = (const float*)d_in[9];
  const float* wq_c   = (const float*)d_in[10];
  const float* wk_c   = (const float*)d_in[11];
  const float* wv_c   = (const float*)d_in[12];
  const float* wo_c   = (const float*)d_in[13];
  const float* bo_c   = (const float*)d_in[14];
  const float* ln2_g  = (const float*)d_in[15];
  const float* ln2_b  = (const float*)d_in[16];
  const float* w1     = (const float*)d_in[17];
  const float* b1     = (const float*)d_in[18];
  const float* w2     = (const float*)d_in[19];
  const float* b2     = (const float*)d_in[20];
  const float* ln3_g  = (const float*)d_in[21];
  const float* ln3_b  = (const float*)d_in[22];

  float* out  = (float*)d_out;             // [16][1024]
  float* slf  = out + 16384;               // [16][16][2048]
  float* enco = out + 16384 + 524288;      // [16][16][2048]

  char* w = (char*)d_ws;
  float*          scr    = (float*)(w + 0x0000000);           // 2 MB
  unsigned short* partb  = (unsigned short*)(w + 0x0200000);  // 32 MB bf16
  float*          msum   = (float*)(w + 0x2200000);           // 128K
  unsigned short* qpb    = (unsigned short*)(w + 0x2240000);  // 512K
  unsigned short* ctxb   = (unsigned short*)(w + 0x22C0000);  // 512K [16][16][1024]
  unsigned short* ob     = (unsigned short*)(w + 0x23C0000);  // 32K  [16][1024]
  float*          x1     = (float*)(w + 0x23D0000);           // 64K
  float*          x2     = (float*)(w + 0x23E0000);           // 64K
  unsigned short* x2b    = (unsigned short*)(w + 0x23F0000);  // 32K
  unsigned short* h1b    = (unsigned short*)(w + 0x2400000);  // 128K
  float*          gpart  = (float*)(w + 0x2500000);           // 1 MB
  float*          fpart  = (float*)(w + 0x2600000);           // 2 MB
  float*          g2part = (float*)(w + 0x2800000);           // 2 MB

  // ---- self attention (instrumented) ----
  g_qp2    <<<256,  256, 0, stream>>>(dec, wq_s, wk_s, qpb, 30);
  g_attn   <<<1024, 256, 0, stream>>>(hist, dec, qpb, scr, partb, msum, 2047, 5);
  g_comb   <<<dim3(4,256), 256, 0, stream>>>(msum, scr, partb, slf, ctxb, 60);
  g_vproj16<<<16,   256, 0, stream>>>(wv_s, ctxb, ob, 60);
  g_skg    <<<dim3(16,16), 256, 0, stream>>>(wo_s, ob, gpart, 1024, 1024, 16, 30);
  g_ln     <<<16,   256, 0, stream>>>(gpart, 16, bo_s, dec, ln1_g, ln1_b, x1, (unsigned short*)0);

  // ---- cross attention (production) ----
  g_qp2    <<<256,  256, 0, stream>>>(x1, wq_c, wk_c, qpb, 1);
  g_attn   <<<1024, 256, 0, stream>>>(enc, dec, qpb, scr, partb, msum, 2048, 1);
  g_comb   <<<dim3(4,256), 256, 0, stream>>>(msum, scr, partb, enco, ctxb, 1);
  g_vproj16<<<16,   256, 0, stream>>>(wv_c, ctxb, ob, 1);
  g_skg    <<<dim3(16,16), 256, 0, stream>>>(wo_c, ob, gpart, 1024, 1024, 16, 1);
  g_ln     <<<16,   256, 0, stream>>>(gpart, 16, bo_c, x1, ln2_g, ln2_b, x2, x2b);

  // ---- FFN + final LN ----
  g_skg    <<<dim3(64,8),  256, 0, stream>>>(w1, x2b, fpart, 4096, 1024, 8, 1);
  g_relu   <<<64,  256, 0, stream>>>(fpart, 8, b1, h1b);
  g_skg    <<<dim3(16,32), 256, 0, stream>>>(w2, h1b, g2part, 1024, 4096, 32, 1);
  g_ln     <<<16,  256, 0, stream>>>(g2part, 32, b2, x2, ln3_g, ln3_b, out, (unsigned short*)0);
}

// Round 12
// 166.827 us; speedup vs baseline: 10.0409x; 10.0409x over previous
//
#include <hip/hip_runtime.h>
#include <hip/hip_bf16.h>
#include <stdint.h>
#include <stddef.h>

// DecoderStepLayer R11: qp-path fixed (measured 18.5us/call: grid 256, 1 blk/CU,
// latency-bound). Now g_qA (MFMA, 128 blks) + g_qB (dot, 256 blks). vproj16
// (9us, 16 blks) reverted to R9 vproj(8,16)+ovred. Rest = R10 production.

#define DEV __device__ __forceinline__

typedef __attribute__((ext_vector_type(8))) short bf16x8;
typedef __attribute__((ext_vector_type(4))) short bf16x4;
typedef __attribute__((ext_vector_type(4))) float f32x4;

DEV unsigned short f2b(float f){
  union { __hip_bfloat16 h; unsigned short u; } cv;
  cv.h = __float2bfloat16(f);
  return cv.u;
}
DEV float b2f(unsigned short u){
  union { unsigned int i; float f; } cv;
  cv.i = ((unsigned int)u) << 16;
  return cv.f;
}
DEV f32x4 mfma16(bf16x8 a, bf16x8 b, f32x4 c){
  return __builtin_amdgcn_mfma_f32_16x16x32_bf16(a, b, c, 0, 0, 0);
}

// ---------------------------------------------------------------------------
// qA: Qpart[h][ks][b][k] = sum_{d' in 128-slice} src[b,d']*wq[h,d',k]
// grid (ks 8, h 16), blk 256. MFMA; A = src f32 rows (cvt), W = wq[h] [1024][64].
__global__ __launch_bounds__(256) void g_qA(const float* __restrict__ src,
    const float* __restrict__ wq, float* __restrict__ Qpart){
  int ks = blockIdx.x, h = blockIdx.y;
  int k0b = ks*128;
  __shared__ unsigned short lt[2][64*40];
  int t = threadIdx.x, lane = t & 63, w = t >> 6;
  int k_loc = t >> 3, n_off = (t & 7)*8;
  const float* apf = src + (size_t)(lane & 15)*1024 + (lane >> 4)*8 + k0b;
  const float* Wb = wq + (size_t)h*65536;      // [1024 d'][64 k] row-major
  f32x4 acc = {0.f,0.f,0.f,0.f};
  float4 x0, x1;
  auto LD = [&](int c){
    const float* wp = Wb + (size_t)(k0b + c*32 + k_loc)*64 + n_off;
    x0 = *(const float4*)wp;
    x1 = *(const float4*)(wp + 4);
  };
  auto ST = [&](int buf){
    unsigned short* p = &lt[buf][0];
    p[(n_off+0)*40 + k_loc] = f2b(x0.x);
    p[(n_off+1)*40 + k_loc] = f2b(x0.y);
    p[(n_off+2)*40 + k_loc] = f2b(x0.z);
    p[(n_off+3)*40 + k_loc] = f2b(x0.w);
    p[(n_off+4)*40 + k_loc] = f2b(x1.x);
    p[(n_off+5)*40 + k_loc] = f2b(x1.y);
    p[(n_off+6)*40 + k_loc] = f2b(x1.z);
    p[(n_off+7)*40 + k_loc] = f2b(x1.w);
  };
  LD(0); ST(0);
  for(int c=0; c<4; ++c){
    if(c+1 < 4) LD(c+1);
    __syncthreads();
    float4 a0 = *(const float4*)(apf + c*32);
    float4 a1 = *(const float4*)(apf + c*32 + 4);
    bf16x8 af;
    af[0]=(short)f2b(a0.x); af[1]=(short)f2b(a0.y);
    af[2]=(short)f2b(a0.z); af[3]=(short)f2b(a0.w);
    af[4]=(short)f2b(a1.x); af[5]=(short)f2b(a1.y);
    af[6]=(short)f2b(a1.z); af[7]=(short)f2b(a1.w);
    bf16x8 bv = *(const bf16x8*)&lt[c&1][(w*16 + (lane & 15))*40 + (lane >> 4)*8];
    acc = mfma16(af, bv, acc);
    if(c+1 < 4) ST((c+1)&1);
  }
  int col = w*16 + (lane & 15);
  int r0 = (lane >> 4)*4;
  #pragma unroll
  for(int i=0;i<4;++i)
    Qpart[ ((size_t)(h*8 + ks)*16 + r0 + i)*64 + col ] = acc[i];
}

// ---------------------------------------------------------------------------
// qB: qpb[b][h][d] = bf16( sum_k wk[h,d,k] * 0.125*sum_ks Qpart[h][ks][b][k] )
// grid (dt 16, h 16), blk 256: d-slice 64 x 16 b; Q reduced+staged in LDS.
__global__ __launch_bounds__(256) void g_qB(const float* __restrict__ wk,
    const float* __restrict__ Qpart, unsigned short* __restrict__ qpb){
  int dt = blockIdx.x, h = blockIdx.y;
  int t = threadIdx.x;
  __shared__ float Qs[1024];               // [b 16][k 64]
  #pragma unroll
  for(int i=0;i<4;++i){
    int idx = i*256 + t;                   // b = idx>>6, k = idx&63
    float s = 0.f;
    #pragma unroll
    for(int ks=0; ks<8; ++ks)
      s += Qpart[((size_t)h<<13) + (ks<<10) + idx];
    Qs[idx] = s * 0.125f;
  }
  __syncthreads();
  int d_loc = t & 63, bg = t >> 6;         // wave-uniform bg -> Qs broadcast
  const float* wr = wk + (size_t)h*65536 + (size_t)(dt*64 + d_loc)*64;
  float acc[4] = {0.f,0.f,0.f,0.f};
  #pragma unroll
  for(int k4=0; k4<16; ++k4){
    float4 w4 = *(const float4*)(wr + k4*4);
    #pragma unroll
    for(int i=0;i<4;++i){
      const float* q = &Qs[(bg*4+i)*64 + k4*4];
      acc[i] += w4.x*q[0] + w4.y*q[1] + w4.z*q[2] + w4.w*q[3];
    }
  }
  #pragma unroll
  for(int i=0;i<4;++i)
    qpb[ ((size_t)(bg*4+i)*16 + h)*1024 + dt*64 + d_loc ] = f2b(acc[i]);
}

// ---------------------------------------------------------------------------
// attn: grid 1024 = (ns 64, b 16). Block = 32 rows, 2 chunks of 16. (22us = BW)
__global__ __launch_bounds__(256) void g_attn(const float* __restrict__ kvsrc,
    const float* __restrict__ decrow, const unsigned short* __restrict__ qpb,
    float* __restrict__ scr, unsigned short* __restrict__ partb,
    float* __restrict__ msum, int lsrc){
  int u = blockIdx.x, ns = u & 63, b = u >> 6;
  int t = threadIdx.x, lane = t & 63, w = t >> 6;
  int r = lane & 15, hi = lane >> 4;
  int slice0 = ns*32;

  __shared__ unsigned short lt[1024*20];
  __shared__ float red[1024];
  __shared__ unsigned short p_lds[16*40];
  __shared__ float f_lds[16];

  float4 ld[16];
  auto ISSUE = [&](int c){
    int row = slice0 + c*16 + r;
    const float* rpp = (row < lsrc) ? kvsrc + ((size_t)b*lsrc + row)*1024
                                    : decrow + (size_t)b*1024;
    rpp += w*256 + hi*8;
    #pragma unroll
    for(int kk=0; kk<8; ++kk){
      ld[kk*2+0] = *(const float4*)(rpp + kk*32);
      ld[kk*2+1] = *(const float4*)(rpp + kk*32 + 4);
    }
  };

  ISSUE(0);
  for(int i=t; i<16*40; i+=256) p_lds[i] = 0;

  bf16x8 qf[8];
  {
    const unsigned short* qp = qpb + ((size_t)b*16 + r)*1024 + w*256 + hi*8;
    #pragma unroll
    for(int kk=0;kk<8;++kk) qf[kk] = *(const bf16x8*)(qp + kk*32);
  }

  f32x4 acc[16];
  #pragma unroll
  for(int i=0;i<16;++i) acc[i] = (f32x4){0.f,0.f,0.f,0.f};
  float m_run = -1e30f, s_run = 0.f;

  __syncthreads();
  for(int c=0; c<2; ++c){
    f32x4 s_acc = {0.f,0.f,0.f,0.f};
    int colw = r ^ ((hi & 1) << 3);
    #pragma unroll
    for(int kk=0; kk<8; ++kk){
      float4 a0 = ld[kk*2], a1 = ld[kk*2+1];
      bf16x8 v;
      v[0]=(short)f2b(a0.x); v[1]=(short)f2b(a0.y);
      v[2]=(short)f2b(a0.z); v[3]=(short)f2b(a0.w);
      v[4]=(short)f2b(a1.x); v[5]=(short)f2b(a1.y);
      v[6]=(short)f2b(a1.z); v[7]=(short)f2b(a1.w);
      unsigned short* pt = &lt[(w*256 + hi*8 + kk*32)*20 + colw];
      #pragma unroll
      for(int j=0;j<8;++j) pt[j*20] = (unsigned short)v[j];
      s_acc = mfma16(v, qf[kk], s_acc);
    }
    if(c < 1) ISSUE(c+1);
    *(f32x4*)&red[t*4] = s_acc;
    __syncthreads();                       // (A)

    f32x4 ss = *(const f32x4*)&red[(0*64+lane)*4];
    ss += *(const f32x4*)&red[(1*64+lane)*4];
    ss += *(const f32x4*)&red[(2*64+lane)*4];
    ss += *(const f32x4*)&red[(3*64+lane)*4];
    float sf[4] = {ss[0], ss[1], ss[2], ss[3]};
    float mc = fmaxf(fmaxf(sf[0],sf[1]), fmaxf(sf[2],sf[3]));
    mc = fmaxf(mc, __shfl_xor(mc, 16));
    mc = fmaxf(mc, __shfl_xor(mc, 32));
    float nm = fmaxf(m_run, mc);
    float fch = __expf(m_run - nm);
    float pvv[4]; float ps = 0.f;
    #pragma unroll
    for(int i=0;i<4;++i){ pvv[i] = __expf(sf[i]-nm); ps += pvv[i]; }
    ps += __shfl_xor(ps, 16);
    ps += __shfl_xor(ps, 32);
    s_run = s_run*fch + ps;
    m_run = nm;
    if(w == 0){
      #pragma unroll
      for(int i=0;i<4;++i) p_lds[r*40 + hi*4 + i] = f2b(pvv[i]);
      if(hi == 0) f_lds[r] = fch;
      float* sp = scr + ((size_t)b*16 + r)*2048 + slice0 + c*16 + hi*4;
      *(float4*)sp = (float4){sf[0], sf[1], sf[2], sf[3]};
    }
    __syncthreads();                       // (B)

    f32x4 fv = *(const f32x4*)&f_lds[hi*4];
    bf16x8 pa = *(const bf16x8*)&p_lds[r*40 + hi*8];
    #pragma unroll
    for(int dc=0; dc<16; ++dc){
      acc[dc] *= fv;
      int d = w*256 + dc*16 + r;
      int col0 = (((hi & 1) ^ ((r >> 3) & 1)) << 3);
      bf16x4 blo = *(const bf16x4*)&lt[d*20 + col0];
      bf16x4 bhi = *(const bf16x4*)&lt[d*20 + col0 + 4];
      bf16x8 bv;
      bv[0]=blo[0]; bv[1]=blo[1]; bv[2]=blo[2]; bv[3]=blo[3];
      bv[4]=bhi[0]; bv[5]=bhi[1]; bv[6]=bhi[2]; bv[7]=bhi[3];
      acc[dc] = mfma16(pa, bv, acc[dc]);
    }
    __syncthreads();                       // (C)
  }
  unsigned short* pl = lt;                 // reuse: [h 16][d 1024]
  #pragma unroll
  for(int dc=0; dc<16; ++dc)
    #pragma unroll
    for(int i=0;i<4;++i)
      pl[(hi*4+i)*1024 + w*256 + dc*16 + r] = f2b(acc[dc][i]);
  __syncthreads();
  {
    const uint4* s4 = (const uint4*)pl;
    uint4* d4 = (uint4*)(partb + (((size_t)b*64 + ns)*16)*1024);
    #pragma unroll
    for(int j=0;j<8;++j) d4[t + j*256] = s4[t + j*256];
  }
  if(w==0 && hi==0){
    msum[(((size_t)b*64 + ns)*16 + r)*2 + 0] = m_run;
    msum[(((size_t)b*64 + ns)*16 + r)*2 + 1] = s_run;
  }
}

// ---------------------------------------------------------------------------
// comb: grid (dq 4, bh 256), blk 256. weights + probs + normalized bf16 ctx.
__global__ __launch_bounds__(256) void g_comb(const float* __restrict__ msum,
    const float* __restrict__ scr, const unsigned short* __restrict__ partb,
    float* __restrict__ attn_out, unsigned short* __restrict__ ctxb){
  int dq = blockIdx.x, bh = blockIdx.y, b = bh >> 4, h = bh & 15;
  int t = threadIdx.x;
  __shared__ float e_lds[64];
  __shared__ float Mi[2];
  if(t < 64){
    float2 ms = *(const float2*)&msum[(((size_t)b*64 + t)*16 + h)*2];
    float M = ms.x;
    #pragma unroll
    for(int o=1; o<64; o<<=1) M = fmaxf(M, __shfl_xor(M, o));
    float e = __expf(ms.x - M)*ms.y;
    float S = e;
    #pragma unroll
    for(int o=1; o<64; o<<=1) S += __shfl_xor(S, o);
    e_lds[t] = __expf(ms.x - M)/S;
    if(t == 0){ Mi[0] = M; Mi[1] = 1.f/S; }
  }
  __syncthreads();
  float M = Mi[0], inv = Mi[1];
  const float* sp = scr + (size_t)bh*2048 + dq*512;
  float* po = attn_out + (size_t)bh*2048 + dq*512;
  po[t]     = __expf(sp[t]     - M)*inv;
  po[t+256] = __expf(sp[t+256] - M)*inv;
  int d = dq*256 + t;
  const unsigned short* pb0 = partb + ((size_t)b*64*16 + h)*1024 + d;
  float acc = 0.f;
  #pragma unroll 8
  for(int ns=0; ns<64; ++ns)
    acc += e_lds[ns]*b2f(pb0[(size_t)ns*16384]);
  ctxb[(size_t)bh*1024 + d] = f2b(acc);
}

// ---------------------------------------------------------------------------
// vproj: opart[h][ks][b][v] = sum_{d in 128-slice} ctxb[b][h][d]*wv[h][d][v]
// grid (ks 8, h 16), blk 256. (R9-verified)
__global__ __launch_bounds__(256) void g_vproj(const float* __restrict__ wv,
    const unsigned short* __restrict__ ctxb, float* __restrict__ opart){
  int ks = blockIdx.x, h = blockIdx.y;
  int k0b = ks*128;
  __shared__ unsigned short lt[2][64*40];
  int t = threadIdx.x, lane = t & 63, w = t >> 6;
  int k_loc = t >> 3, n_off = (t & 7)*8;
  const unsigned short* apb = ctxb + (size_t)(lane & 15)*16384 + (size_t)h*1024
                              + (lane >> 4)*8 + k0b;
  const float* Wb = wv + (size_t)h*65536;      // [1024 d][64 v]
  f32x4 acc = {0.f,0.f,0.f,0.f};
  float4 x0, x1;
  auto LD = [&](int c){
    const float* wp = Wb + (size_t)(k0b + c*32 + k_loc)*64 + n_off;
    x0 = *(const float4*)wp;
    x1 = *(const float4*)(wp + 4);
  };
  auto ST = [&](int buf){
    unsigned short* p = &lt[buf][0];
    p[(n_off+0)*40 + k_loc] = f2b(x0.x);
    p[(n_off+1)*40 + k_loc] = f2b(x0.y);
    p[(n_off+2)*40 + k_loc] = f2b(x0.z);
    p[(n_off+3)*40 + k_loc] = f2b(x0.w);
    p[(n_off+4)*40 + k_loc] = f2b(x1.x);
    p[(n_off+5)*40 + k_loc] = f2b(x1.y);
    p[(n_off+6)*40 + k_loc] = f2b(x1.z);
    p[(n_off+7)*40 + k_loc] = f2b(x1.w);
  };
  LD(0); ST(0);
  for(int c=0; c<4; ++c){
    if(c+1 < 4) LD(c+1);
    __syncthreads();
    bf16x8 af = *(const bf16x8*)(apb + c*32);
    bf16x8 bv = *(const bf16x8*)&lt[c&1][(w*16 + (lane & 15))*40 + (lane >> 4)*8];
    acc = mfma16(af, bv, acc);
    if(c+1 < 4) ST((c+1)&1);
  }
  int col = w*16 + (lane & 15);
  int r0 = (lane >> 4)*4;
  #pragma unroll
  for(int i=0;i<4;++i)
    opart[ ((size_t)(h*8 + ks)*16 + r0 + i)*64 + col ] = acc[i];
}

// ovred: ob[b][h*64+v] = bf16( sum_ks(8) opart ). grid 64, blk 256.
__global__ __launch_bounds__(256) void g_ovred(const float* __restrict__ opart,
    unsigned short* __restrict__ ob){
  int i = blockIdx.x*256 + threadIdx.x;    // 16384
  int b = i >> 10, hv = i & 1023, h = hv >> 6, v = hv & 63;
  float s = 0.f;
  #pragma unroll
  for(int ks=0; ks<8; ++ks)
    s += opart[ ((size_t)(h*8 + ks)*16 + b)*64 + v ];
  ob[(size_t)b*1024 + hv] = f2b(s);
}

// ---------------------------------------------------------------------------
// LN( sum_ks parts + bias + resid ) * g + bb -> xout [+ bf16]. grid 16.
__global__ __launch_bounds__(256) void g_ln(const float* __restrict__ parts, int KS,
    const float* __restrict__ bias, const float* __restrict__ resid,
    const float* __restrict__ g, const float* __restrict__ bb,
    float* __restrict__ xout, unsigned short* __restrict__ xb16){
  int b = blockIdx.x, t = threadIdx.x;
  __shared__ float red[256];
  const float4* bias4  = (const float4*)bias;
  const float4* resid4 = (const float4*)resid + (size_t)b*256;
  const float4* parts4 = (const float4*)parts;
  float4 s = bias4[t];
  { float4 rr = resid4[t]; s.x+=rr.x; s.y+=rr.y; s.z+=rr.z; s.w+=rr.w; }
  #pragma unroll 4
  for(int k=0;k<KS;++k){
    float4 pp = parts4[((size_t)k*16 + b)*256 + t];
    s.x+=pp.x; s.y+=pp.y; s.z+=pp.z; s.w+=pp.w;
  }
  red[t] = s.x+s.y+s.z+s.w; __syncthreads();
  for(int off=128; off>0; off>>=1){ if(t<off) red[t]+=red[t+off]; __syncthreads(); }
  float mean = red[0]*(1.f/1024.f); __syncthreads();
  float dx=s.x-mean, dy=s.y-mean, dz=s.z-mean, dw=s.w-mean;
  red[t] = dx*dx+dy*dy+dz*dz+dw*dw; __syncthreads();
  for(int off=128; off>0; off>>=1){ if(t<off) red[t]+=red[t+off]; __syncthreads(); }
  float rstd = rsqrtf(red[0]*(1.f/1024.f) + 1e-5f);
  float4 g4 = ((const float4*)g)[t], b4 = ((const float4*)bb)[t];
  float4 y;
  y.x = dx*rstd*g4.x + b4.x;
  y.y = dy*rstd*g4.y + b4.y;
  y.z = dz*rstd*g4.z + b4.z;
  y.w = dw*rstd*g4.w + b4.w;
  if(xout) ((float4*)xout)[(size_t)b*256 + t] = y;
  if(xb16){
    ushort4 uu;
    uu.x = f2b(y.x); uu.y = f2b(y.y); uu.z = f2b(y.z); uu.w = f2b(y.w);
    ((ushort4*)xb16)[(size_t)b*256 + t] = uu;
  }
}

// ---------------------------------------------------------------------------
// skinny GEMM: part[ks,b,n] = A[16,Kslice] @ W[Kslice,N]
__global__ __launch_bounds__(256) void g_skg(const float* __restrict__ W,
    const unsigned short* __restrict__ A, float* __restrict__ part,
    int N, int K, int KS){
  int nt = blockIdx.x, ks = blockIdx.y;
  int Ksl = K / KS, k0b = ks * Ksl, n0 = nt*64;
  int nc = Ksl >> 5;
  __shared__ unsigned short lt[2][64*40];
  int t = threadIdx.x, lane = t & 63, w = t >> 6;
  int k_loc = t >> 3, n_off = (t & 7)*8;
  const unsigned short* apb = A + (size_t)(lane & 15)*K + (lane >> 4)*8 + k0b;
  f32x4 acc = {0.f,0.f,0.f,0.f};
  float4 x0, x1;
  auto LD = [&](int c){
    const float* wp = W + (size_t)(k0b + c*32 + k_loc)*N + n0 + n_off;
    x0 = *(const float4*)wp;
    x1 = *(const float4*)(wp + 4);
  };
  auto ST = [&](int buf){
    unsigned short* p = &lt[buf][0];
    p[(n_off+0)*40 + k_loc] = f2b(x0.x);
    p[(n_off+1)*40 + k_loc] = f2b(x0.y);
    p[(n_off+2)*40 + k_loc] = f2b(x0.z);
    p[(n_off+3)*40 + k_loc] = f2b(x0.w);
    p[(n_off+4)*40 + k_loc] = f2b(x1.x);
    p[(n_off+5)*40 + k_loc] = f2b(x1.y);
    p[(n_off+6)*40 + k_loc] = f2b(x1.z);
    p[(n_off+7)*40 + k_loc] = f2b(x1.w);
  };
  LD(0); ST(0);
  for(int c=0; c<nc; ++c){
    if(c+1 < nc) LD(c+1);
    __syncthreads();
    bf16x8 af = *(const bf16x8*)(apb + c*32);
    bf16x8 bv = *(const bf16x8*)&lt[c&1][(w*16 + (lane & 15))*40 + (lane >> 4)*8];
    acc = mfma16(af, bv, acc);
    if(c+1 < nc) ST((c+1)&1);
  }
  int col = n0 + w*16 + (lane & 15);
  int r0 = (lane >> 4)*4;
  #pragma unroll
  for(int i=0;i<4;++i)
    part[ ((size_t)ks*16 + r0 + i)*(size_t)N + col ] = acc[i];
}

// relu( sum_ks fparts + b1 ) -> h1 bf16 [16][4096]. grid 64.
__global__ __launch_bounds__(256) void g_relu(const float* __restrict__ parts, int KS,
    const float* __restrict__ b1, unsigned short* __restrict__ h1){
  int i = blockIdx.x*256 + threadIdx.x;
  int b = i >> 10, f4 = i & 1023;
  float4 s = ((const float4*)b1)[f4];
  #pragma unroll 4
  for(int k=0;k<KS;++k){
    float4 pp = ((const float4*)parts)[((size_t)k*16 + b)*1024 + f4];
    s.x+=pp.x; s.y+=pp.y; s.z+=pp.z; s.w+=pp.w;
  }
  ushort4 uu;
  uu.x = f2b(fmaxf(s.x,0.f)); uu.y = f2b(fmaxf(s.y,0.f));
  uu.z = f2b(fmaxf(s.z,0.f)); uu.w = f2b(fmaxf(s.w,0.f));
  ((ushort4*)h1)[i] = uu;
}

// ---------------------------------------------------------------------------
extern "C" void kernel_launch(void* const* d_in, const int* in_sizes, int n_in,
                              void* d_out, int out_size, void* d_ws, size_t ws_size,
                              hipStream_t stream){
  const float* dec    = (const float*)d_in[0];
  const float* hist   = (const float*)d_in[1];
  const float* enc    = (const float*)d_in[2];
  const float* wq_s   = (const float*)d_in[3];
  const float* wk_s   = (const float*)d_in[4];
  const float* wv_s   = (const float*)d_in[5];
  const float* wo_s   = (const float*)d_in[6];
  const float* bo_s   = (const float*)d_in[7];
  const float* ln1_g  = (const float*)d_in[8];
  const float* ln1_b  = (const float*)d_in[9];
  const float* wq_c   = (const float*)d_in[10];
  const float* wk_c   = (const float*)d_in[11];
  const float* wv_c   = (const float*)d_in[12];
  const float* wo_c   = (const float*)d_in[13];
  const float* bo_c   = (const float*)d_in[14];
  const float* ln2_g  = (const float*)d_in[15];
  const float* ln2_b  = (const float*)d_in[16];
  const float* w1     = (const float*)d_in[17];
  const float* b1     = (const float*)d_in[18];
  const float* w2     = (const float*)d_in[19];
  const float* b2     = (const float*)d_in[20];
  const float* ln3_g  = (const float*)d_in[21];
  const float* ln3_b  = (const float*)d_in[22];

  float* out  = (float*)d_out;             // [16][1024]
  float* slf  = out + 16384;               // [16][16][2048]
  float* enco = out + 16384 + 524288;      // [16][16][2048]

  char* w = (char*)d_ws;
  float*          scr    = (float*)(w + 0x0000000);           // 2 MB
  unsigned short* partb  = (unsigned short*)(w + 0x0200000);  // 32 MB bf16
  float*          msum   = (float*)(w + 0x2200000);           // 128K
  unsigned short* qpb    = (unsigned short*)(w + 0x2240000);  // 512K
  unsigned short* ctxb   = (unsigned short*)(w + 0x22C0000);  // 512K [16][16][1024]
  float*          Qpart  = (float*)(w + 0x2340000);           // 512K [16][8][16][64]
  float*          opart  = (float*)(w + 0x23C0000);           // 512K [16][8][16][64]
  unsigned short* ob     = (unsigned short*)(w + 0x2440000);  // 32K  [16][1024]
  float*          x1     = (float*)(w + 0x2450000);           // 64K
  float*          x2     = (float*)(w + 0x2460000);           // 64K
  unsigned short* x2b    = (unsigned short*)(w + 0x2470000);  // 32K
  unsigned short* h1b    = (unsigned short*)(w + 0x2480000);  // 128K
  float*          gpart  = (float*)(w + 0x2500000);           // 1 MB
  float*          fpart  = (float*)(w + 0x2600000);           // 2 MB
  float*          g2part = (float*)(w + 0x2800000);           // 2 MB

  // ---- self attention ----
  g_qA   <<<dim3(8,16),  256, 0, stream>>>(dec, wq_s, Qpart);
  g_qB   <<<dim3(16,16), 256, 0, stream>>>(wk_s, Qpart, qpb);
  g_attn <<<1024, 256, 0, stream>>>(hist, dec, qpb, scr, partb, msum, 2047);
  g_comb <<<dim3(4,256), 256, 0, stream>>>(msum, scr, partb, slf, ctxb);
  g_vproj<<<dim3(8,16),  256, 0, stream>>>(wv_s, ctxb, opart);
  g_ovred<<<64,   256, 0, stream>>>(opart, ob);
  g_skg  <<<dim3(16,16), 256, 0, stream>>>(wo_s, ob, gpart, 1024, 1024, 16);
  g_ln   <<<16,   256, 0, stream>>>(gpart, 16, bo_s, dec, ln1_g, ln1_b, x1, (unsigned short*)0);

  // ---- cross attention ----
  g_qA   <<<dim3(8,16),  256, 0, stream>>>(x1, wq_c, Qpart);
  g_qB   <<<dim3(16,16), 256, 0, stream>>>(wk_c, Qpart, qpb);
  g_attn <<<1024, 256, 0, stream>>>(enc, dec, qpb, scr, partb, msum, 2048);
  g_comb <<<dim3(4,256), 256, 0, stream>>>(msum, scr, partb, enco, ctxb);
  g_vproj<<<dim3(8,16),  256, 0, stream>>>(wv_c, ctxb, opart);
  g_ovred<<<64,   256, 0, stream>>>(opart, ob);
  g_skg  <<<dim3(16,16), 256, 0, stream>>>(wo_c, ob, gpart, 1024, 1024, 16);
  g_ln   <<<16,   256, 0, stream>>>(gpart, 16, bo_c, x1, ln2_g, ln2_b, x2, x2b);

  // ---- FFN + final LN ----
  g_skg  <<<dim3(64,8),  256, 0, stream>>>(w1, x2b, fpart, 4096, 1024, 8);
  g_relu <<<64,  256, 0, stream>>>(fpart, 8, b1, h1b);
  g_skg  <<<dim3(16,32), 256, 0, stream>>>(w2, h1b, g2part, 1024, 4096, 32);
  g_ln   <<<16,  256, 0, stream>>>(g2part, 32, b2, x2, ln3_g, ln3_b, out, (unsigned short*)0);
}